// Round 6
// baseline (293.883 us; speedup 1.0000x reference)
//
#include <hip/hip_runtime.h>

typedef unsigned short ushort_t;
typedef __attribute__((ext_vector_type(8))) short bf16x8;
typedef __attribute__((ext_vector_type(4))) float f32x4;

#define B_SZ   16
#define NQ     4096
#define NKV    77
#define QDIM   320
#define CDIM   768
#define HEADS  8
#define DHEAD  64
#define INNER  512
#define M_ROWS (B_SZ * NQ)   // 65536
#define VT_STR 104

__device__ __forceinline__ ushort_t f2bf(float f) {
  unsigned u = __builtin_bit_cast(unsigned, f);
  u = (u + 0x7fffu + ((u >> 16) & 1u)) >> 16;
  return (ushort_t)u;
}

__device__ __forceinline__ void async16(const ushort_t* g, ushort_t* l) {
  __builtin_amdgcn_global_load_lds(
      (const __attribute__((address_space(1))) unsigned int*)g,
      (__attribute__((address_space(3))) unsigned int*)l,
      16, 0, 0);
}

// ---------------- mask dtype detect + bias table ----------------
__global__ void mask_bias_kernel(const unsigned char* __restrict__ mraw,
                                 float* __restrict__ biasT) {
  __shared__ int s_u8, s_w4;
  if (threadIdx.x == 0) { s_u8 = 0; s_w4 = 0; }
  __syncthreads();
  const int nbytes = B_SZ * NKV;
  for (int i = threadIdx.x; i < nbytes; i += blockDim.x) {
    unsigned char v = mraw[i];
    if (v && (i & 3)) atomicOr(&s_u8, 1);
    if (v && ((i & 7) == 4)) atomicOr(&s_w4, 1);
  }
  __syncthreads();
  int mode = s_u8 ? 0 : (s_w4 ? 1 : 2);
  for (int i = threadIdx.x; i < B_SZ * 80; i += blockDim.x) {
    int b = i / 80, kv = i - b * 80;
    float bias = -2e30f;
    if (kv < NKV) {
      int idx = b * NKV + kv;
      long long m;
      if (mode == 0)      m = (long long)mraw[idx];
      else if (mode == 1) m = (long long)((const int*)mraw)[idx];
      else                m = ((const long long*)mraw)[idx];
      bias = m ? 0.0f : -1e30f;
    }
    biasT[i] = bias;
  }
}

// ---------------- casts ----------------
__global__ void cast_f32_bf16(const float* __restrict__ in,
                              ushort_t* __restrict__ out, int n4) {
  int i = blockIdx.x * blockDim.x + threadIdx.x;
  int stride = gridDim.x * blockDim.x;
  const float4* in4 = (const float4*)in;
  ushort4* out4 = (ushort4*)out;
  for (; i < n4; i += stride) {
    float4 v = in4[i];
    ushort4 o;
    o.x = f2bf(v.x); o.y = f2bf(v.y); o.z = f2bf(v.z); o.w = f2bf(v.w);
    out4[i] = o;
  }
}

__global__ void tcast_f32_bf16(const float* __restrict__ in,
                               ushort_t* __restrict__ out,
                               int K, int N, int Npad, float scale) {
  int i = blockIdx.x * blockDim.x + threadIdx.x;
  int stride = gridDim.x * blockDim.x;
  int total = Npad * K;
  for (; i < total; i += stride) {
    int n = i / K, k = i - n * K;
    out[i] = (n < N) ? f2bf(in[(size_t)k * N + n] * scale) : (ushort_t)0;
  }
}

__global__ void vtrans_kernel(const ushort_t* __restrict__ kvb,
                              ushort_t* __restrict__ vt) {
  const int h = blockIdx.y, b = blockIdx.z;
  const int wid = threadIdx.x >> 6, lane = threadIdx.x & 63;
  const int d = blockIdx.x * 4 + wid;
  ushort_t* dst = vt + (size_t)(b * HEADS + h) * (64 * VT_STR) + d * VT_STR;
  for (int kv = lane; kv < VT_STR; kv += 64)
    dst[kv] = (kv < NKV)
        ? kvb[(size_t)(b * NKV + kv) * 1024 + 512 + h * 64 + d]
        : (ushort_t)0;
}

// ---------------- generic 128x128 GEMM (small kv projection only) ----------
__global__ __launch_bounds__(256) void gemm_bf16(
    const ushort_t* __restrict__ A, const ushort_t* __restrict__ Bt,
    ushort_t* __restrict__ Cb,
    int K, int Astride, int Bstride, int Cstride) {
  __shared__ ushort_t As[128 * 64];
  __shared__ ushort_t Bs[128 * 64];
  const int tid = threadIdx.x;
  const int wid = tid >> 6, lane = tid & 63;
  const int wr = wid >> 1, wc = wid & 1;
  const int tileM = blockIdx.x * 128, tileN = blockIdx.y * 128;

  f32x4 acc[4][4];
#pragma unroll
  for (int m = 0; m < 4; ++m)
#pragma unroll
    for (int n = 0; n < 4; ++n) acc[m][n] = (f32x4){0.f, 0.f, 0.f, 0.f};

  const int srow = lane >> 3;
  const int scol = (lane & 7) * 8;

  for (int kt = 0; kt < K; kt += 64) {
    __syncthreads();
#pragma unroll
    for (int j = 0; j < 4; ++j) {
      int s = wid * 4 + j;
      const ushort_t* ga = A + (size_t)(tileM + s * 8 + srow) * Astride + kt + scol;
      const ushort_t* gb = Bt + (size_t)(tileN + s * 8 + srow) * Bstride + kt + scol;
      async16(ga, As + s * 512);
      async16(gb, Bs + s * 512);
    }
    __syncthreads();
#pragma unroll
    for (int kc = 0; kc < 2; ++kc) {
      bf16x8 af[4], bfr[4];
#pragma unroll
      for (int m = 0; m < 4; ++m)
        af[m] = *(const bf16x8*)&As[(wr * 64 + m * 16 + (lane & 15)) * 64 + kc * 32 + (lane >> 4) * 8];
#pragma unroll
      for (int n = 0; n < 4; ++n)
        bfr[n] = *(const bf16x8*)&Bs[(wc * 64 + n * 16 + (lane & 15)) * 64 + kc * 32 + (lane >> 4) * 8];
#pragma unroll
      for (int m = 0; m < 4; ++m)
#pragma unroll
        for (int n = 0; n < 4; ++n)
          acc[m][n] = __builtin_amdgcn_mfma_f32_16x16x32_bf16(af[m], bfr[n], acc[m][n], 0, 0, 0);
    }
  }

  const int r0 = tileM + wr * 64;
  const int c0 = tileN + wc * 64;
  const int rl2 = (lane >> 4) * 4;
  const int cl = lane & 15;
#pragma unroll
  for (int m = 0; m < 4; ++m)
#pragma unroll
    for (int n = 0; n < 4; ++n) {
      int col = c0 + n * 16 + cl;
#pragma unroll
      for (int r = 0; r < 4; ++r)
        Cb[(size_t)(r0 + m * 16 + rl2 + r) * Cstride + col] = f2bf(acc[m][n][r]);
    }
}

// ---------------- q-proj v3: streaming, B from L2, one barrier pair --------
// 1024 blocks x (64 rows x full N=512). 8 waves (2M x 4N), wave = 32x128.
// Stage whole A-tile [64][320] f32 (80 KB) via global_load_lds with
// source-side XOR swizzle; single __syncthreads; K-loop barrier-free with
// B-frags loaded straight from L2-resident Wt. Epilogue via LDS bounce.
__global__ __launch_bounds__(512, 2) void gemm_qproj_v3(
    const float* __restrict__ x, const ushort_t* __restrict__ Wt,
    ushort_t* __restrict__ qb) {
  extern __shared__ char sm[];
  const int tid = threadIdx.x, wid = tid >> 6, lane = tid & 63;
  const int rl = lane & 15, g = lane >> 4;
  const int wr = wid & 1, wc = wid >> 1;
  const size_t Mbase = (size_t)blockIdx.x * 64;
  const char* xB = (const char*)x;

  // stage A: 64 rows x 80 chunks of 16B; chunk slot c16 holds source c16^(row&7)
#pragma unroll
  for (int i = 0; i < 10; ++i) {
    unsigned c = tid + i * 512;
    unsigned row = c / 80u, c16 = c - row * 80u;
    size_t src = (Mbase + row) * 1280 + (size_t)((c16 ^ (row & 7u)) * 16);
    async16((const ushort_t*)(xB + src), (ushort_t*)(sm + c * 16));
  }
  __syncthreads();

  f32x4 acc[2][8];
#pragma unroll
  for (int m = 0; m < 2; ++m)
#pragma unroll
    for (int n = 0; n < 8; ++n) acc[m][n] = (f32x4){0.f, 0.f, 0.f, 0.f};

#pragma unroll
  for (int kc = 0; kc < 10; ++kc) {
    bf16x8 bfr[8];
#pragma unroll
    for (int n = 0; n < 8; ++n)
      bfr[n] = *(const bf16x8*)&Wt[(size_t)(wc * 128 + n * 16 + rl) * QDIM + kc * 32 + g * 8];
    bf16x8 af[2];
#pragma unroll
    for (int m = 0; m < 2; ++m) {
      const int row = wr * 32 + m * 16 + rl;
      const int sw = (row & 7) << 4;
      f32x4 lo = *(const f32x4*)(sm + row * 1280 + ((kc * 128 + g * 32) ^ sw));
      f32x4 hi = *(const f32x4*)(sm + row * 1280 + ((kc * 128 + g * 32 + 16) ^ sw));
      unsigned w0, w1, w2, w3;
      asm("v_cvt_pk_bf16_f32 %0, %1, %2" : "=v"(w0) : "v"(lo[0]), "v"(lo[1]));
      asm("v_cvt_pk_bf16_f32 %0, %1, %2" : "=v"(w1) : "v"(lo[2]), "v"(lo[3]));
      asm("v_cvt_pk_bf16_f32 %0, %1, %2" : "=v"(w2) : "v"(hi[0]), "v"(hi[1]));
      asm("v_cvt_pk_bf16_f32 %0, %1, %2" : "=v"(w3) : "v"(hi[2]), "v"(hi[3]));
      union { unsigned u[4]; bf16x8 v; } cv;
      cv.u[0] = w0; cv.u[1] = w1; cv.u[2] = w2; cv.u[3] = w3;
      af[m] = cv.v;
    }
#pragma unroll
    for (int m = 0; m < 2; ++m)
#pragma unroll
      for (int n = 0; n < 8; ++n)
        acc[m][n] = __builtin_amdgcn_mfma_f32_16x16x32_bf16(af[m], bfr[n], acc[m][n], 0, 0, 0);
  }

  // epilogue: acc -> eb (stride 528, conflict-free) -> coalesced 16B stores
  __syncthreads();
  ushort_t* eb = (ushort_t*)sm;
#pragma unroll
  for (int m = 0; m < 2; ++m)
#pragma unroll
    for (int n = 0; n < 8; ++n)
#pragma unroll
      for (int r = 0; r < 4; ++r)
        eb[(wr * 32 + m * 16 + g * 4 + r) * 528 + wc * 128 + n * 16 + rl] = f2bf(acc[m][n][r]);
  __syncthreads();
#pragma unroll
  for (int i = 0; i < 8; ++i) {
    unsigned flat = tid + i * 512;
    unsigned row = flat >> 6, c8 = flat & 63;
    *(bf16x8*)(qb + (Mbase + row) * INNER + c8 * 8) =
        *(const bf16x8*)(sm + row * 1056 + c8 * 16);
  }
}

// ---------------- out-proj v3: streaming, B from L2, one barrier -----------
// 1024 blocks x (64 rows x full N=384). 8 waves (2M x 4N), wave = 32x96.
// Stage whole A-tile [64][512] bf16 (64 KB); barrier-free K-loop (16 steps).
__global__ __launch_bounds__(512, 2) void gemm_oproj_v3(
    const ushort_t* __restrict__ A, const ushort_t* __restrict__ Wt,
    const float* __restrict__ bo, float* __restrict__ out) {
  extern __shared__ char sm[];
  const int tid = threadIdx.x, wid = tid >> 6, lane = tid & 63;
  const int rl = lane & 15, g = lane >> 4;
  const int wr = wid & 1, wc = wid >> 1;
  const size_t Mbase = (size_t)blockIdx.x * 64;
  const char* AB = (const char*)A;

  // stage A: 64 rows x 64 chunks of 16B, XOR-swizzled source
#pragma unroll
  for (int i = 0; i < 8; ++i) {
    unsigned c = tid + i * 512;
    unsigned row = c >> 6, c16 = c & 63;
    size_t src = (Mbase + row) * 1024 + (size_t)((c16 ^ (row & 7u)) * 16);
    async16((const ushort_t*)(AB + src), (ushort_t*)(sm + c * 16));
  }
  __syncthreads();

  f32x4 acc[2][6];
#pragma unroll
  for (int m = 0; m < 2; ++m)
#pragma unroll
    for (int n = 0; n < 6; ++n) acc[m][n] = (f32x4){0.f, 0.f, 0.f, 0.f};

#pragma unroll 4
  for (int kc = 0; kc < 16; ++kc) {
    bf16x8 bfr[6];
#pragma unroll
    for (int n = 0; n < 6; ++n)
      bfr[n] = *(const bf16x8*)&Wt[(size_t)(wc * 96 + n * 16 + rl) * INNER + kc * 32 + g * 8];
    bf16x8 af[2];
#pragma unroll
    for (int m = 0; m < 2; ++m) {
      const int row = wr * 32 + m * 16 + rl;
      af[m] = *(const bf16x8*)(sm + row * 1024 + ((kc * 64 + g * 16) ^ ((row & 7) << 4)));
    }
#pragma unroll
    for (int m = 0; m < 2; ++m)
#pragma unroll
      for (int n = 0; n < 6; ++n)
        acc[m][n] = __builtin_amdgcn_mfma_f32_16x16x32_bf16(af[m], bfr[n], acc[m][n], 0, 0, 0);
  }

  // epilogue: direct f32 stores (64B-contiguous per 16-lane group) + bias
#pragma unroll
  for (int n = 0; n < 6; ++n) {
    int col = wc * 96 + n * 16 + rl;
    if (col < QDIM) {
      float bv = bo[col];
#pragma unroll
      for (int m = 0; m < 2; ++m)
#pragma unroll
        for (int r = 0; r < 4; ++r)
          out[(Mbase + wr * 32 + m * 16 + g * 4 + r) * QDIM + col] = acc[m][n][r] + bv;
    }
  }
}

// ---------------- fused attention (unchanged) ----------------
__global__ __launch_bounds__(256) void attn_kernel(
    const ushort_t* __restrict__ qb, const ushort_t* __restrict__ kvb,
    const ushort_t* __restrict__ vt, const float* __restrict__ biasT,
    ushort_t* __restrict__ ab) {
  __shared__ ushort_t Vt[64 * VT_STR];
  __shared__ ushort_t P[4 * 16 * VT_STR];
  const int qt = blockIdx.x, h = blockIdx.y, b = blockIdx.z;
  const int tid = threadIdx.x, wid = tid >> 6, lane = tid & 63;
  const int rl = lane & 15;
  const int kh = (lane >> 4) * 8;

  const ushort_t* vtg = vt + (size_t)(b * HEADS + h) * (64 * VT_STR);
  for (int i = tid; i < 832; i += 256) async16(vtg + i * 8, Vt + i * 8);
  for (int i = tid; i < 832; i += 256)
    *(bf16x8*)&P[i * 8] = (bf16x8){0, 0, 0, 0, 0, 0, 0, 0};

  bf16x8 kf[5][2];
  float bias_v[5];
#pragma unroll
  for (int nt = 0; nt < 5; ++nt) {
    int kv = nt * 16 + rl;
    bias_v[nt] = biasT[b * 80 + kv];
    kf[nt][0] = (bf16x8){0, 0, 0, 0, 0, 0, 0, 0};
    kf[nt][1] = (bf16x8){0, 0, 0, 0, 0, 0, 0, 0};
    if (kv < NKV) {
      const ushort_t* kp = &kvb[(size_t)(b * NKV + kv) * 1024 + h * 64 + kh];
      kf[nt][0] = *(const bf16x8*)kp;
      kf[nt][1] = *(const bf16x8*)(kp + 32);
    }
  }
  __syncthreads();

  const int qbase = b * NQ + qt * 256;
  const int pbase = wid * (16 * VT_STR);
#pragma unroll 1
  for (int chunk = 0; chunk < 4; ++chunk) {
    if (chunk) __syncthreads();
    const int row0 = chunk * 64 + wid * 16;

    const ushort_t* qp = &qb[(size_t)(qbase + row0 + rl) * INNER + h * 64 + kh];
    bf16x8 qf0 = *(const bf16x8*)qp;
    bf16x8 qf1 = *(const bf16x8*)(qp + 32);

    f32x4 s[5];
#pragma unroll
    for (int nt = 0; nt < 5; ++nt) {
      s[nt] = (f32x4){0.f, 0.f, 0.f, 0.f};
      s[nt] = __builtin_amdgcn_mfma_f32_16x16x32_bf16(qf0, kf[nt][0], s[nt], 0, 0, 0);
      s[nt] = __builtin_amdgcn_mfma_f32_16x16x32_bf16(qf1, kf[nt][1], s[nt], 0, 0, 0);
    }

    float mx[4] = {-3.0e38f, -3.0e38f, -3.0e38f, -3.0e38f};
#pragma unroll
    for (int nt = 0; nt < 5; ++nt)
#pragma unroll
      for (int r = 0; r < 4; ++r) {
        float v = s[nt][r] + bias_v[nt];
        s[nt][r] = v;
        mx[r] = fmaxf(mx[r], v);
      }
#pragma unroll
    for (int d = 1; d < 16; d <<= 1)
#pragma unroll
      for (int r = 0; r < 4; ++r) mx[r] = fmaxf(mx[r], __shfl_xor(mx[r], d, 64));

    float sm_[4] = {0.f, 0.f, 0.f, 0.f};
#pragma unroll
    for (int nt = 0; nt < 5; ++nt)
#pragma unroll
      for (int r = 0; r < 4; ++r) {
        float p = __expf(s[nt][r] - mx[r]);
        s[nt][r] = p;
        sm_[r] += p;
      }
#pragma unroll
    for (int d = 1; d < 16; d <<= 1)
#pragma unroll
      for (int r = 0; r < 4; ++r) sm_[r] += __shfl_xor(sm_[r], d, 64);

    float rcp[4];
#pragma unroll
    for (int r = 0; r < 4; ++r) rcp[r] = 1.0f / sm_[r];

#pragma unroll
    for (int nt = 0; nt < 5; ++nt)
#pragma unroll
      for (int r = 0; r < 4; ++r)
        P[pbase + ((lane >> 4) * 4 + r) * VT_STR + nt * 16 + rl] = f2bf(s[nt][r]);

    f32x4 o[4];
#pragma unroll
    for (int n = 0; n < 4; ++n) o[n] = (f32x4){0.f, 0.f, 0.f, 0.f};
#pragma unroll
    for (int kc = 0; kc < 3; ++kc) {
      bf16x8 pf = *(const bf16x8*)&P[pbase + rl * VT_STR + kc * 32 + kh];
#pragma unroll
      for (int n = 0; n < 4; ++n) {
        bf16x8 vf = *(const bf16x8*)&Vt[(n * 16 + rl) * VT_STR + kc * 32 + kh];
        o[n] = __builtin_amdgcn_mfma_f32_16x16x32_bf16(pf, vf, o[n], 0, 0, 0);
      }
    }

#pragma unroll
    for (int n = 0; n < 4; ++n)
#pragma unroll
      for (int r = 0; r < 4; ++r)
        P[pbase + ((lane >> 4) * 4 + r) * VT_STR + n * 16 + rl] = f2bf(o[n][r] * rcp[r]);

    __syncthreads();

    {
      const int rflat = tid >> 2, d0 = (tid & 3) * 16;
      const ushort_t* src = &P[(rflat >> 4) * (16 * VT_STR) + (rflat & 15) * VT_STR + d0];
      ushort_t* dst = &ab[(size_t)(qbase + chunk * 64 + rflat) * INNER + h * 64 + d0];
      *(bf16x8*)dst = *(const bf16x8*)src;
      *(bf16x8*)(dst + 8) = *(const bf16x8*)(src + 8);
    }
  }
}

// ---------------- host ----------------
extern "C" void kernel_launch(void* const* d_in, const int* in_sizes, int n_in,
                              void* d_out, int out_size, void* d_ws, size_t ws_size,
                              hipStream_t stream) {
  (void)in_sizes; (void)n_in; (void)out_size; (void)ws_size;
  const float* x   = (const float*)d_in[0];
  const float* ctx = (const float*)d_in[1];
  const unsigned char* mask = (const unsigned char*)d_in[2];
  const float* Wq = (const float*)d_in[3];
  const float* Wk = (const float*)d_in[4];
  const float* Wv = (const float*)d_in[5];
  const float* Wo = (const float*)d_in[6];
  const float* bo = (const float*)d_in[7];
  float* out = (float*)d_out;

  hipFuncSetAttribute((const void*)gemm_qproj_v3,
                      hipFuncAttributeMaxDynamicSharedMemorySize, 81920);
  hipFuncSetAttribute((const void*)gemm_oproj_v3,
                      hipFuncAttributeMaxDynamicSharedMemorySize, 65536);

  char* ws = (char*)d_ws;
  size_t off = 0;
  auto alloc = [&](size_t bytes) {
    char* p = ws + off;
    off += (bytes + 255) & ~(size_t)255;
    return p;
  };
  float*    biasT = (float*)alloc(B_SZ * 80 * sizeof(float));
  ushort_t* ab    = (ushort_t*)alloc((size_t)M_ROWS * INNER * 2);
  ushort_t* qb    = (ushort_t*)alloc((size_t)M_ROWS * INNER * 2);
  ushort_t* cb    = (ushort_t*)alloc((size_t)1280 * CDIM * 2);
  ushort_t* Wqb   = (ushort_t*)alloc((size_t)INNER * QDIM * 2);
  ushort_t* Wkvb  = (ushort_t*)alloc((size_t)1024 * CDIM * 2);
  ushort_t* Wob   = (ushort_t*)alloc((size_t)384 * INNER * 2);
  ushort_t* kvb   = (ushort_t*)alloc((size_t)1280 * 1024 * 2);
  ushort_t* vt    = (ushort_t*)alloc((size_t)B_SZ * HEADS * 64 * VT_STR * 2);

  mask_bias_kernel<<<1, 256, 0, stream>>>(mask, biasT);
  cast_f32_bf16<<<512, 256, 0, stream>>>(ctx, cb, B_SZ * NKV * CDIM / 4);
  tcast_f32_bf16<<<640, 256, 0, stream>>>(Wq, Wqb, QDIM, INNER, INNER, 0.125f);
  tcast_f32_bf16<<<1536, 256, 0, stream>>>(Wk, Wkvb, CDIM, INNER, INNER, 1.0f);
  tcast_f32_bf16<<<1536, 256, 0, stream>>>(Wv, Wkvb + (size_t)INNER * CDIM, CDIM, INNER, INNER, 1.0f);
  tcast_f32_bf16<<<768, 256, 0, stream>>>(Wo, Wob, INNER, QDIM, 384, 1.0f);

  // q = bf16(x) @ (0.125*Wq) — streaming, B from L2, one barrier pair
  gemm_qproj_v3<<<M_ROWS / 64, 512, 81920, stream>>>(x, Wqb, qb);
  // [k|v] = ctx @ [Wk|Wv]
  dim3 g2(1280 / 128, 1024 / 128);
  gemm_bf16<<<g2, 256, 0, stream>>>(cb, Wkvb, kvb, CDIM, CDIM, CDIM, 1024);
  // V -> vt[b][h][d][104]
  vtrans_kernel<<<dim3(16, HEADS, B_SZ), 256, 0, stream>>>(kvb, vt);
  // attention
  attn_kernel<<<dim3(NQ / 256, HEADS, B_SZ), 256, 0, stream>>>(qb, kvb, vt, biasT, ab);
  // out = ab @ Wo + bo — streaming, B from L2
  gemm_oproj_v3<<<M_ROWS / 64, 512, 65536, stream>>>(ab, Wob, bo, out);
}

// Round 7
// 205.328 us; speedup vs baseline: 1.4313x; 1.4313x over previous
//
#include <hip/hip_runtime.h>

typedef unsigned short ushort_t;
typedef __attribute__((ext_vector_type(8))) short bf16x8;
typedef __attribute__((ext_vector_type(4))) float f32x4;

#define B_SZ   16
#define NQ     4096
#define NKV    77
#define QDIM   320
#define CDIM   768
#define HEADS  8
#define DHEAD  64
#define INNER  512
#define M_ROWS (B_SZ * NQ)   // 65536
#define VT_STR 104

__device__ __forceinline__ ushort_t f2bf(float f) {
  unsigned u = __builtin_bit_cast(unsigned, f);
  u = (u + 0x7fffu + ((u >> 16) & 1u)) >> 16;
  return (ushort_t)u;
}

__device__ __forceinline__ void async16(const ushort_t* g, ushort_t* l) {
  __builtin_amdgcn_global_load_lds(
      (const __attribute__((address_space(1))) unsigned int*)g,
      (__attribute__((address_space(3))) unsigned int*)l,
      16, 0, 0);
}

// ---------------- mask dtype detect + bias table ----------------
__global__ void mask_bias_kernel(const unsigned char* __restrict__ mraw,
                                 float* __restrict__ biasT) {
  __shared__ int s_u8, s_w4;
  if (threadIdx.x == 0) { s_u8 = 0; s_w4 = 0; }
  __syncthreads();
  const int nbytes = B_SZ * NKV;
  for (int i = threadIdx.x; i < nbytes; i += blockDim.x) {
    unsigned char v = mraw[i];
    if (v && (i & 3)) atomicOr(&s_u8, 1);
    if (v && ((i & 7) == 4)) atomicOr(&s_w4, 1);
  }
  __syncthreads();
  int mode = s_u8 ? 0 : (s_w4 ? 1 : 2);
  for (int i = threadIdx.x; i < B_SZ * 80; i += blockDim.x) {
    int b = i / 80, kv = i - b * 80;
    float bias = -2e30f;
    if (kv < NKV) {
      int idx = b * NKV + kv;
      long long m;
      if (mode == 0)      m = (long long)mraw[idx];
      else if (mode == 1) m = (long long)((const int*)mraw)[idx];
      else                m = ((const long long*)mraw)[idx];
      bias = m ? 0.0f : -1e30f;
    }
    biasT[i] = bias;
  }
}

// ---------------- casts ----------------
__global__ void cast_f32_bf16(const float* __restrict__ in,
                              ushort_t* __restrict__ out, int n4) {
  int i = blockIdx.x * blockDim.x + threadIdx.x;
  int stride = gridDim.x * blockDim.x;
  const float4* in4 = (const float4*)in;
  ushort4* out4 = (ushort4*)out;
  for (; i < n4; i += stride) {
    float4 v = in4[i];
    ushort4 o;
    o.x = f2bf(v.x); o.y = f2bf(v.y); o.z = f2bf(v.z); o.w = f2bf(v.w);
    out4[i] = o;
  }
}

__global__ void tcast_f32_bf16(const float* __restrict__ in,
                               ushort_t* __restrict__ out,
                               int K, int N, int Npad, float scale) {
  int i = blockIdx.x * blockDim.x + threadIdx.x;
  int stride = gridDim.x * blockDim.x;
  int total = Npad * K;
  for (; i < total; i += stride) {
    int n = i / K, k = i - n * K;
    out[i] = (n < N) ? f2bf(in[(size_t)k * N + n] * scale) : (ushort_t)0;
  }
}

__global__ void vtrans_kernel(const ushort_t* __restrict__ kvb,
                              ushort_t* __restrict__ vt) {
  const int h = blockIdx.y, b = blockIdx.z;
  const int wid = threadIdx.x >> 6, lane = threadIdx.x & 63;
  const int d = blockIdx.x * 4 + wid;
  ushort_t* dst = vt + (size_t)(b * HEADS + h) * (64 * VT_STR) + d * VT_STR;
  for (int kv = lane; kv < VT_STR; kv += 64)
    dst[kv] = (kv < NKV)
        ? kvb[(size_t)(b * NKV + kv) * 1024 + 512 + h * 64 + d]
        : (ushort_t)0;
}

// ---------------- generic 128x128 GEMM (kv projection only) ----------
__global__ __launch_bounds__(256) void gemm_bf16(
    const ushort_t* __restrict__ A, const ushort_t* __restrict__ Bt,
    ushort_t* __restrict__ Cb,
    int K, int Astride, int Bstride, int Cstride) {
  __shared__ ushort_t As[128 * 64];
  __shared__ ushort_t Bs[128 * 64];
  const int tid = threadIdx.x;
  const int wid = tid >> 6, lane = tid & 63;
  const int wr = wid >> 1, wc = wid & 1;
  const int tileM = blockIdx.x * 128, tileN = blockIdx.y * 128;

  f32x4 acc[4][4];
#pragma unroll
  for (int m = 0; m < 4; ++m)
#pragma unroll
    for (int n = 0; n < 4; ++n) acc[m][n] = (f32x4){0.f, 0.f, 0.f, 0.f};

  const int srow = lane >> 3;
  const int scol = (lane & 7) * 8;

  for (int kt = 0; kt < K; kt += 64) {
    __syncthreads();
#pragma unroll
    for (int j = 0; j < 4; ++j) {
      int s = wid * 4 + j;
      const ushort_t* ga = A + (size_t)(tileM + s * 8 + srow) * Astride + kt + scol;
      const ushort_t* gb = Bt + (size_t)(tileN + s * 8 + srow) * Bstride + kt + scol;
      async16(ga, As + s * 512);
      async16(gb, Bs + s * 512);
    }
    __syncthreads();
#pragma unroll
    for (int kc = 0; kc < 2; ++kc) {
      bf16x8 af[4], bfr[4];
#pragma unroll
      for (int m = 0; m < 4; ++m)
        af[m] = *(const bf16x8*)&As[(wr * 64 + m * 16 + (lane & 15)) * 64 + kc * 32 + (lane >> 4) * 8];
#pragma unroll
      for (int n = 0; n < 4; ++n)
        bfr[n] = *(const bf16x8*)&Bs[(wc * 64 + n * 16 + (lane & 15)) * 64 + kc * 32 + (lane >> 4) * 8];
#pragma unroll
      for (int m = 0; m < 4; ++m)
#pragma unroll
        for (int n = 0; n < 4; ++n)
          acc[m][n] = __builtin_amdgcn_mfma_f32_16x16x32_bf16(af[m], bfr[n], acc[m][n], 0, 0, 0);
    }
  }

  const int r0 = tileM + wr * 64;
  const int c0 = tileN + wc * 64;
  const int rl2 = (lane >> 4) * 4;
  const int cl = lane & 15;
#pragma unroll
  for (int m = 0; m < 4; ++m)
#pragma unroll
    for (int n = 0; n < 4; ++n) {
      int col = c0 + n * 16 + cl;
#pragma unroll
      for (int r = 0; r < 4; ++r)
        Cb[(size_t)(r0 + m * 16 + rl2 + r) * Cstride + col] = f2bf(acc[m][n][r]);
    }
}

// ======================= MEGA: qproj + attention + oproj ====================
// Block = (64 q-rows, batch b). 512 threads = 8 waves; wave w <-> head w.
// LDS plan (byte offsets, phases alias dead regions):
//   phase1: xs[64][328] bf16 @0 (41984) + ws1[512][40] @41984 (40960)
//   phase2: qt 8x[64][72] @0 (73728) -> P 8x[16][104] @0 (26624)
//   phase3: al[64][516] @0 (66048) + ws2[384][40] @66048 (30720) -> 96768 total
__global__ __launch_bounds__(512, 2) void mega_kernel(
    const float* __restrict__ x, const ushort_t* __restrict__ Wqb,
    const ushort_t* __restrict__ kvb, const ushort_t* __restrict__ vt,
    const float* __restrict__ biasT, const ushort_t* __restrict__ Wob,
    const float* __restrict__ bo, float* __restrict__ out) {
  extern __shared__ char sm[];
  ushort_t* const xs  = (ushort_t*)sm;             // [64][328]
  ushort_t* const ws1 = (ushort_t*)(sm + 41984);   // [512][40]
  ushort_t* const qtb = (ushort_t*)sm;             // 8 x [64][72]
  ushort_t* const Plb = (ushort_t*)sm;             // 8 x [16][104]
  ushort_t* const al  = (ushort_t*)sm;             // [64][516]
  ushort_t* const ws2 = (ushort_t*)(sm + 66048);   // [384][40]

  const int tid = threadIdx.x, wid = tid >> 6, lane = tid & 63;
  const int rl = lane & 15, g = lane >> 4;
  const int b = blockIdx.y, h = wid;
  const size_t Mbase = (size_t)b * NQ + (size_t)blockIdx.x * 64;
  const bf16x8 zf = (bf16x8){0, 0, 0, 0, 0, 0, 0, 0};

  // ---- issue x loads (HBM critical path) ----
  float4 xr[10];
#pragma unroll
  for (int i = 0; i < 10; ++i) {
    int c = tid + i * 512;
    int row = c / 80, c4 = c - row * 80;
    xr[i] = ((const float4*)x)[(Mbase + row) * 80 + c4];
  }

  // ---- K fragments + bias for my head (L2; overlaps x latency) ----
  bf16x8 kf[5][2];
  float bias_v[5];
#pragma unroll
  for (int nt = 0; nt < 5; ++nt) {
    int kv = nt * 16 + rl;
    bias_v[nt] = biasT[b * 80 + kv];
    kf[nt][0] = zf; kf[nt][1] = zf;
    if (kv < NKV) {
      const ushort_t* kp = &kvb[(size_t)(b * NKV + kv) * 1024 + h * 64 + g * 8];
      kf[nt][0] = *(const bf16x8*)kp;
      kf[nt][1] = *(const bf16x8*)(kp + 32);
    }
  }

  // ---- phase 0: x -> bf16 LDS ----
#pragma unroll
  for (int i = 0; i < 10; ++i) {
    int c = tid + i * 512;
    int row = c / 80, c4 = c - row * 80;
    ushort4 u;
    u.x = f2bf(xr[i].x); u.y = f2bf(xr[i].y);
    u.z = f2bf(xr[i].z); u.w = f2bf(xr[i].w);
    *(ushort4*)&xs[row * 328 + c4 * 4] = u;
  }
  // preload Wq chunk 0 (issue-early)
  bf16x8 wreg[4];
#pragma unroll
  for (int i = 0; i < 4; ++i) {
    int c = tid + i * 512, row = c >> 2, c16 = c & 3;
    wreg[i] = *(const bf16x8*)&Wqb[(size_t)row * QDIM + c16 * 8];
  }
  __syncthreads();  // xs ready

  // ---- phase 1: GEMM1  q[64][512] = xs @ Wq^T  (wave tile 64 x 64) ----
  f32x4 acc1[4][4];
#pragma unroll
  for (int m = 0; m < 4; ++m)
#pragma unroll
    for (int n = 0; n < 4; ++n) acc1[m][n] = (f32x4){0.f, 0.f, 0.f, 0.f};

  for (int kc = 0; kc < 10; ++kc) {
#pragma unroll
    for (int i = 0; i < 4; ++i) {
      int c = tid + i * 512, row = c >> 2, c16 = c & 3;
      *(bf16x8*)&ws1[row * 40 + c16 * 8] = wreg[i];
    }
    if (kc < 9) {
#pragma unroll
      for (int i = 0; i < 4; ++i) {
        int c = tid + i * 512, row = c >> 2, c16 = c & 3;
        wreg[i] = *(const bf16x8*)&Wqb[(size_t)row * QDIM + (kc + 1) * 32 + c16 * 8];
      }
    }
    __syncthreads();  // ws1(kc) ready; next-chunk loads stay in flight
    bf16x8 af[4], bfr[4];
#pragma unroll
    for (int m = 0; m < 4; ++m)
      af[m] = *(const bf16x8*)&xs[(m * 16 + rl) * 328 + kc * 32 + g * 8];
#pragma unroll
    for (int n = 0; n < 4; ++n)
      bfr[n] = *(const bf16x8*)&ws1[(wid * 64 + n * 16 + rl) * 40 + g * 8];
#pragma unroll
    for (int m = 0; m < 4; ++m)
#pragma unroll
      for (int n = 0; n < 4; ++n)
        acc1[m][n] = __builtin_amdgcn_mfma_f32_16x16x32_bf16(af[m], bfr[n], acc1[m][n], 0, 0, 0);
    __syncthreads();  // everyone done reading ws1/xs before next write
  }

  // ---- phase 2a: Q transpose via wave-private LDS (aliases xs/ws1) ----
  ushort_t* qw = qtb + wid * 4608;  // [64][72] shorts
#pragma unroll
  for (int m = 0; m < 4; ++m)
#pragma unroll
    for (int n = 0; n < 4; ++n)
#pragma unroll
      for (int r = 0; r < 4; ++r)
        qw[(m * 16 + g * 4 + r) * 72 + n * 16 + rl] = f2bf(acc1[m][n][r]);
  bf16x8 qf[4][2];
#pragma unroll
  for (int m = 0; m < 4; ++m) {
    qf[m][0] = *(const bf16x8*)&qw[(m * 16 + rl) * 72 + g * 8];
    qf[m][1] = *(const bf16x8*)&qw[(m * 16 + rl) * 72 + 32 + g * 8];
  }
  __syncthreads();  // all qf read; qt space may be reused as P

  // ---- phase 2b: attention, head h, 4 m-tiles of 16 rows ----
  ushort_t* Pw = Plb + wid * 1664;  // [16][104] shorts
  for (int i = lane; i < 208; i += 64) *(bf16x8*)&Pw[i * 8] = zf;

  const ushort_t* vtg = vt + (size_t)(b * HEADS + h) * (64 * VT_STR);
  f32x4 o[4][4];
#pragma unroll
  for (int m = 0; m < 4; ++m)
#pragma unroll
    for (int n = 0; n < 4; ++n) o[m][n] = (f32x4){0.f, 0.f, 0.f, 0.f};
  float mrcp[4][4];

#pragma unroll
  for (int m = 0; m < 4; ++m) {
    f32x4 s[5];
#pragma unroll
    for (int nt = 0; nt < 5; ++nt) {
      s[nt] = (f32x4){0.f, 0.f, 0.f, 0.f};
      s[nt] = __builtin_amdgcn_mfma_f32_16x16x32_bf16(qf[m][0], kf[nt][0], s[nt], 0, 0, 0);
      s[nt] = __builtin_amdgcn_mfma_f32_16x16x32_bf16(qf[m][1], kf[nt][1], s[nt], 0, 0, 0);
    }
    float mx[4] = {-3.0e38f, -3.0e38f, -3.0e38f, -3.0e38f};
#pragma unroll
    for (int nt = 0; nt < 5; ++nt)
#pragma unroll
      for (int r = 0; r < 4; ++r) {
        float v = s[nt][r] + bias_v[nt];
        s[nt][r] = v;
        mx[r] = fmaxf(mx[r], v);
      }
#pragma unroll
    for (int d = 1; d < 16; d <<= 1)
#pragma unroll
      for (int r = 0; r < 4; ++r) mx[r] = fmaxf(mx[r], __shfl_xor(mx[r], d, 64));
    float sum[4] = {0.f, 0.f, 0.f, 0.f};
#pragma unroll
    for (int nt = 0; nt < 5; ++nt)
#pragma unroll
      for (int r = 0; r < 4; ++r) {
        float p = __expf(s[nt][r] - mx[r]);
        s[nt][r] = p;
        sum[r] += p;
      }
#pragma unroll
    for (int d = 1; d < 16; d <<= 1)
#pragma unroll
      for (int r = 0; r < 4; ++r) sum[r] += __shfl_xor(sum[r], d, 64);
#pragma unroll
    for (int r = 0; r < 4; ++r) mrcp[m][r] = 1.0f / sum[r];

#pragma unroll
    for (int nt = 0; nt < 5; ++nt)
#pragma unroll
      for (int r = 0; r < 4; ++r)
        Pw[(g * 4 + r) * VT_STR + nt * 16 + rl] = f2bf(s[nt][r]);

#pragma unroll
    for (int kc = 0; kc < 3; ++kc) {
      bf16x8 pf = *(const bf16x8*)&Pw[rl * VT_STR + kc * 32 + g * 8];
#pragma unroll
      for (int n = 0; n < 4; ++n) {
        bf16x8 vf = *(const bf16x8*)&vtg[(n * 16 + rl) * VT_STR + kc * 32 + g * 8];
        o[m][n] = __builtin_amdgcn_mfma_f32_16x16x32_bf16(pf, vf, o[m][n], 0, 0, 0);
      }
    }
  }
  __syncthreads();  // all P reads done; region becomes al

  // ---- phase 3: a -> LDS, GEMM2 out[64][320] = a @ Wo^T + bo ----
#pragma unroll
  for (int m = 0; m < 4; ++m)
#pragma unroll
    for (int n = 0; n < 4; ++n)
#pragma unroll
      for (int r = 0; r < 4; ++r)
        al[(m * 16 + g * 4 + r) * 516 + wid * 64 + n * 16 + rl] =
            f2bf(o[m][n][r] * mrcp[m][r]);

  bf16x8 w2[3];
#pragma unroll
  for (int i = 0; i < 3; ++i) {
    int c = tid + i * 512, row = c >> 2, c16 = c & 3;
    w2[i] = *(const bf16x8*)&Wob[(size_t)row * INNER + c16 * 8];
  }
  __syncthreads();  // al ready

  const int wr2 = wid & 1, wc2 = wid >> 1;
  f32x4 acc2[2][6];
#pragma unroll
  for (int m = 0; m < 2; ++m)
#pragma unroll
    for (int n = 0; n < 6; ++n) acc2[m][n] = (f32x4){0.f, 0.f, 0.f, 0.f};

  for (int kc = 0; kc < 16; ++kc) {
#pragma unroll
    for (int i = 0; i < 3; ++i) {
      int c = tid + i * 512, row = c >> 2, c16 = c & 3;
      *(bf16x8*)&ws2[row * 40 + c16 * 8] = w2[i];
    }
    if (kc < 15) {
#pragma unroll
      for (int i = 0; i < 3; ++i) {
        int c = tid + i * 512, row = c >> 2, c16 = c & 3;
        w2[i] = *(const bf16x8*)&Wob[(size_t)row * INNER + (kc + 1) * 32 + c16 * 8];
      }
    }
    __syncthreads();  // ws2(kc) ready
    bf16x8 af2[2], bf2[6];
#pragma unroll
    for (int m = 0; m < 2; ++m)
      af2[m] = *(const bf16x8*)&al[(wr2 * 32 + m * 16 + rl) * 516 + kc * 32 + g * 8];
#pragma unroll
    for (int n = 0; n < 6; ++n)
      bf2[n] = *(const bf16x8*)&ws2[(wc2 * 96 + n * 16 + rl) * 40 + g * 8];
#pragma unroll
    for (int m = 0; m < 2; ++m)
#pragma unroll
      for (int n = 0; n < 6; ++n)
        acc2[m][n] = __builtin_amdgcn_mfma_f32_16x16x32_bf16(af2[m], bf2[n], acc2[m][n], 0, 0, 0);
    __syncthreads();
  }

  // ---- epilogue: f32 + bias, predicated col < 320 ----
#pragma unroll
  for (int n = 0; n < 6; ++n) {
    int col = wc2 * 96 + n * 16 + rl;
    if (col < QDIM) {
      float bv = bo[col];
#pragma unroll
      for (int m = 0; m < 2; ++m)
#pragma unroll
        for (int r = 0; r < 4; ++r)
          out[(Mbase + wr2 * 32 + m * 16 + g * 4 + r) * QDIM + col] = acc2[m][n][r] + bv;
    }
  }
}

// ---------------- host ----------------
extern "C" void kernel_launch(void* const* d_in, const int* in_sizes, int n_in,
                              void* d_out, int out_size, void* d_ws, size_t ws_size,
                              hipStream_t stream) {
  (void)in_sizes; (void)n_in; (void)out_size; (void)ws_size;
  const float* x   = (const float*)d_in[0];
  const float* ctx = (const float*)d_in[1];
  const unsigned char* mask = (const unsigned char*)d_in[2];
  const float* Wq = (const float*)d_in[3];
  const float* Wk = (const float*)d_in[4];
  const float* Wv = (const float*)d_in[5];
  const float* Wo = (const float*)d_in[6];
  const float* bo = (const float*)d_in[7];
  float* out = (float*)d_out;

  hipFuncSetAttribute((const void*)mega_kernel,
                      hipFuncAttributeMaxDynamicSharedMemorySize, 98304);

  char* ws = (char*)d_ws;
  size_t off = 0;
  auto alloc = [&](size_t bytes) {
    char* p = ws + off;
    off += (bytes + 255) & ~(size_t)255;
    return p;
  };
  float*    biasT = (float*)alloc(B_SZ * 80 * sizeof(float));
  ushort_t* cb    = (ushort_t*)alloc((size_t)1280 * CDIM * 2);
  ushort_t* Wqb   = (ushort_t*)alloc((size_t)INNER * QDIM * 2);   // (0.125*Wq)^T [512][320]
  ushort_t* Wkvb  = (ushort_t*)alloc((size_t)1024 * CDIM * 2);    // [[Wk^T];[Wv^T]]
  ushort_t* Wob   = (ushort_t*)alloc((size_t)384 * INNER * 2);    // Wo^T pad [384][512]
  ushort_t* kvb   = (ushort_t*)alloc((size_t)1280 * 1024 * 2);
  ushort_t* vt    = (ushort_t*)alloc((size_t)B_SZ * HEADS * 64 * VT_STR * 2);

  mask_bias_kernel<<<1, 256, 0, stream>>>(mask, biasT);
  cast_f32_bf16<<<512, 256, 0, stream>>>(ctx, cb, B_SZ * NKV * CDIM / 4);
  tcast_f32_bf16<<<640, 256, 0, stream>>>(Wq, Wqb, QDIM, INNER, INNER, 0.125f);
  tcast_f32_bf16<<<1536, 256, 0, stream>>>(Wk, Wkvb, CDIM, INNER, INNER, 1.0f);
  tcast_f32_bf16<<<1536, 256, 0, stream>>>(Wv, Wkvb + (size_t)INNER * CDIM, CDIM, INNER, INNER, 1.0f);
  tcast_f32_bf16<<<768, 256, 0, stream>>>(Wo, Wob, INNER, QDIM, 384, 1.0f);

  // [k|v] = ctx @ [Wk|Wv]
  dim3 g2(1280 / 128, 1024 / 128);
  gemm_bf16<<<g2, 256, 0, stream>>>(cb, Wkvb, kvb, CDIM, CDIM, CDIM, 1024);
  // V -> vt[b][h][d][104]
  vtrans_kernel<<<dim3(16, HEADS, B_SZ), 256, 0, stream>>>(kvb, vt);

  // fused qproj + attention + oproj (no qb/ab intermediates)
  mega_kernel<<<dim3(NQ / 64, B_SZ), 512, 96768, stream>>>(
      x, Wqb, kvb, vt, biasT, Wob, bo, out);
}